// Round 4
// baseline (307.598 us; speedup 1.0000x reference)
//
#include <hip/hip_runtime.h>

#define N_NODES 50000
#define N_EDGES 1600000
#define DIM 64
#define NBK 196          // buckets of 256 dst-nodes
#define BIN_BLOCKS 391   // ceil(1.6M / 4096)
#define CSR_CAP 12288    // per-bucket slots
#define QCAP 3072        // per-quarter slots (mult-16-padded mean ~2560, ~8-sigma margin)
#define GEMM_BLOCKS 197  // covers 50000 rows + dummy zero row
#define NB_AGGQ 12500    // sliced agg blocks: 4 quarters x 3125 chunks of 16 nodes
#define TG_BLOCKS 196    // tanh+W2 blocks: 196*256 = 50176 >= 50001

// f32 -> bf16 round-to-nearest-even
__device__ __forceinline__ unsigned short f2bf(float f) {
    union { float f; unsigned u; } v; v.f = f;
    unsigned r = v.u + 0x7FFF + ((v.u >> 16) & 1);
    return (unsigned short)(r >> 16);
}
__device__ __forceinline__ float bf2f(unsigned short h) {
    union { unsigned u; float f; } v; v.u = ((unsigned)h) << 16;  return v.f;
}
// packed-bf16 halves of a uint -> f32 (low ushort, high ushort)
__device__ __forceinline__ float blo(unsigned u) {
    union { unsigned u; float f; } v; v.u = u << 16; return v.f;
}
__device__ __forceinline__ float bhi(unsigned u) {
    union { unsigned u; float f; } v; v.u = u & 0xFFFF0000u; return v.f;
}

// R11-verbatim fused kernel: blocks [0, BIN_BLOCKS) bin edges into per-bucket
// regions (bcur zero-based, memset first); blocks [BIN_BLOCKS, ..) T=feat@W1^T.
__global__ __launch_bounds__(256) void bin_and_gemm1(const int* __restrict__ src,
                                                     const int* __restrict__ dst,
                                                     int* __restrict__ bcur,
                                                     int* __restrict__ binned,
                                                     const float* __restrict__ X,
                                                     const float* __restrict__ W,
                                                     unsigned short* __restrict__ T) {
    __shared__ int cnt[NBK];
    __shared__ int lofs[NBK];
    __shared__ int shiftv[NBK];
    __shared__ int sb[256];
    __shared__ int stag[4096];
    __shared__ unsigned char stb[4096];
    __shared__ float Ws[64 * 64];
    int tid = threadIdx.x;

    if (blockIdx.x >= BIN_BLOCKS) {
        // ---------------- GEMM path (feat f32 -> T bf16) ----------------
#pragma unroll
        for (int j = 0; j < 16; ++j) Ws[j * 256 + tid] = W[j * 256 + tid];
        __syncthreads();

        int n = (blockIdx.x - BIN_BLOCKS) * 256 + tid;
        if (n > N_NODES) return;
        ushort4* tp = (ushort4*)(T + (size_t)n * 64);
        if (n == N_NODES) {  // dummy zero row (pad target for agg1)
            ushort4 z = {0, 0, 0, 0};
#pragma unroll
            for (int k = 0; k < 16; ++k) tp[k] = z;
            return;
        }

        float4 x[16];
        const float4* xp = (const float4*)(X + (size_t)n * 64);
#pragma unroll
        for (int k = 0; k < 16; ++k) x[k] = xp[k];

        for (int fg = 0; fg < 16; ++fg) {
            float r[4];
#pragma unroll
            for (int fi = 0; fi < 4; ++fi) {
                int f = fg * 4 + fi;
                float acc = 0.f;
#pragma unroll
                for (int k4 = 0; k4 < 16; ++k4) {
                    float4 w = *(const float4*)&Ws[f * 64 + k4 * 4];
                    float4 xv = x[k4];
                    acc += xv.x * w.x + xv.y * w.y + xv.z * w.z + xv.w * w.w;
                }
                r[fi] = acc;
            }
            ushort4 o;
            o.x = f2bf(r[0]); o.y = f2bf(r[1]); o.z = f2bf(r[2]); o.w = f2bf(r[3]);
            tp[fg] = o;
        }
        return;
    }

    // ---------------- Binning path (R6-proven) ----------------
    if (tid < NBK) cnt[tid] = 0;
    __syncthreads();

    int base = blockIdx.x * 4096;
    int nedge = N_EDGES - base;
    if (nedge > 4096) nedge = 4096;

    int myb[16], myr[16], myp[16];
#pragma unroll
    for (int i = 0; i < 16; ++i) {
        int e = base + i * 256 + tid;
        myb[i] = -1;
        if (e < N_EDGES) {
            int s = src[e], d = dst[e];
            int b = d >> 8;
            myb[i] = b;
            myp[i] = ((d & 255) << 16) | s;
            myr[i] = atomicAdd(&cnt[b], 1);
        }
    }
    __syncthreads();

    int c = (tid < NBK) ? cnt[tid] : 0;
    sb[tid] = c;
    __syncthreads();
    for (int off = 1; off < 256; off <<= 1) {
        int u = (tid >= off) ? sb[tid - off] : 0;
        __syncthreads();
        sb[tid] += u;
        __syncthreads();
    }
    if (tid < NBK) {
        lofs[tid] = sb[tid] - c;
        if (c) shiftv[tid] = tid * CSR_CAP + atomicAdd(&bcur[tid * 16], c) - lofs[tid];
    }
    __syncthreads();

#pragma unroll
    for (int i = 0; i < 16; ++i) {
        if (myb[i] >= 0) {
            int idx = lofs[myb[i]] + myr[i];
            stag[idx] = myp[i];
            stb[idx] = (unsigned char)myb[i];
        }
    }
    __syncthreads();

    for (int i = tid; i < nedge; i += 256)
        binned[i + shiftv[stb[i]]] = stag[i];
}

// R11-verbatim: one workgroup per (bucket, dst-quarter). Counts padded to
// mult-16 with dummy src = N_NODES (zero row). nodeinfo=(pcnt<<23)|pos, pos%16==0.
__global__ __launch_bounds__(256) void build_csr(const int* __restrict__ binned,
                                                 const int* __restrict__ bcur,
                                                 unsigned* __restrict__ nodeinfo,
                                                 unsigned short* __restrict__ csr16) {
    __shared__ int cnt[64], cnt2[64], ofs[64], sb[64];
    __shared__ int qtot;
    int tid = threadIdx.x;
    int b = blockIdx.x >> 2;
    int q = blockIdx.x & 3;
    int ibase = b * CSR_CAP;
    int qbase = (b * 4 + q) * QCAP;
    int m = bcur[b * 16];          // zero-based bucket edge count
    if (m > CSR_CAP) m = CSR_CAP;
    if (tid < 64) { cnt[tid] = 0; cnt2[tid] = 0; }
    __syncthreads();

    for (int i = tid; i < m; i += 256) {
        int dl = (binned[ibase + i] >> 16) & 255;
        if ((dl >> 6) == q) atomicAdd(&cnt[dl & 63], 1);
    }
    __syncthreads();

    int v = 0;
    if (tid < 64) { v = (cnt[tid] + 15) & ~15; sb[tid] = v; }  // mult-16 pad
    __syncthreads();
    for (int off = 1; off < 64; off <<= 1) {
        int u = (tid >= off && tid < 64) ? sb[tid - off] : 0;
        __syncthreads();
        if (tid < 64) sb[tid] += u;
        __syncthreads();
    }
    if (tid < 64) {
        ofs[tid] = sb[tid] - v;
        int node = (b << 8) + (q << 6) + tid;
        if (node < N_NODES)
            nodeinfo[node] = ((unsigned)v << 23) | (unsigned)(qbase + ofs[tid]);
    }
    if (tid == 63) qtot = sb[63];
    __syncthreads();

    int qt = qtot;
    for (int i = tid; i < qt; i += 256) csr16[qbase + i] = (unsigned short)N_NODES;
    __syncthreads();

    for (int i = tid; i < m; i += 256) {
        int p = binned[ibase + i];
        int dl = (p >> 16) & 255;
        if ((dl >> 6) == q) {
            int r = atomicAdd(&cnt2[dl & 63], 1);
            csr16[qbase + ofs[dl & 63] + r] = (unsigned short)(p & 0xFFFF);
        }
    }
}

// Accumulate one uint4 (8 bf16 feature values) into 8 f32 accumulators.
#define ACC8(d)                                                     \
    a0 += blo(d.x); a1 += bhi(d.x); a2 += blo(d.y); a3 += bhi(d.y); \
    a4 += blo(d.z); a5 += bhi(d.z); a6 += blo(d.w); a7 += bhi(d.w);

// R18: quarter-sliced gather-aggregate. Each block handles 16 nodes x a
// 16-feature slice (32B per T row). quarter = blockIdx&3 rides the assumed
// round-robin block->XCD dispatch so each XCD gathers only a 1.6MB column
// slice of SRC -> L2-resident (the R17 falsification: gather was
// latency-bound on L3/HBM because 6.4MB T thrashed the 4MB per-XCD L2).
// blockIdx -> (q, chunk) bijection: q=b&3, c=((b>>3)<<1)|((b>>2)&1), c<3125.
// Wave layout: 2 nodes/wave; lane = node_sub(1) | group(4) | fhalf(1);
// one uint4 load = 32 row-slices/wave. Reduce via LDS (stride 17: conflict-
// free reads). csr/nodeinfo nontemporal (don't evict the T slice); output
// nontemporal stores. DST layout: dstp[node*64 + q*16 + f] (f32).
template <bool ADD_BIAS_ONLY>  // true: out = bias + agg (f32 final); same code path
__global__ __launch_bounds__(512) void agg_q(const unsigned short* __restrict__ T,
                                             const unsigned short* __restrict__ csr,
                                             const unsigned* __restrict__ nodeinfo,
                                             const float* __restrict__ bias,
                                             float* __restrict__ dstp) {
    __shared__ float part[8][2][16][17];   // 17.4 KB
    int tid = threadIdx.x;
    int w = tid >> 6, lane = tid & 63;
    int ns = lane >> 5;           // node within wave (0/1)
    int g  = (lane >> 1) & 15;    // edge group (16-edge chunk layout)
    int fs = lane & 1;            // feature half (8 features each)
    int q  = blockIdx.x & 3;
    int c  = ((blockIdx.x >> 3) << 1) | ((blockIdx.x >> 2) & 1);
    int node = c * 16 + w * 2 + ns;

    unsigned info = __builtin_nontemporal_load(nodeinfo + node);
    int pos = (int)(info & 0x7FFFFFu);
    int nt16 = (int)(info >> 23) >> 4;    // 16-edge chunks (pcnt mult 16)
    const unsigned short* ip = csr + pos + g;
    const uint4* Tp = (const uint4*)T;
    int qo = q * 2 + fs;                  // uint4 column within the 8-uint4 row
    float a0 = 0.f, a1 = 0.f, a2 = 0.f, a3 = 0.f, a4 = 0.f, a5 = 0.f, a6 = 0.f, a7 = 0.f;
    int k = 0;
    for (; k + 2 <= nt16; k += 2) {
        int j0 = __builtin_nontemporal_load(ip + k * 16);
        int j1 = __builtin_nontemporal_load(ip + k * 16 + 16);
        uint4 d0 = Tp[(size_t)j0 * 8 + qo];
        uint4 d1 = Tp[(size_t)j1 * 8 + qo];
        ACC8(d0) ACC8(d1)
    }
    if (k < nt16) {
        int j0 = __builtin_nontemporal_load(ip + k * 16);
        uint4 d0 = Tp[(size_t)j0 * 8 + qo];
        ACC8(d0)
    }
    // scalar LDS writes (stride-17 rows; 17 coprime 32 -> near-conflict-free)
    float* pp = &part[w][ns][g][fs * 8];
    pp[0] = a0; pp[1] = a1; pp[2] = a2; pp[3] = a3;
    pp[4] = a4; pp[5] = a5; pp[6] = a6; pp[7] = a7;
    // part[w] is wave-private: wave-internal DS ordering suffices (R17-proven)

    if (lane < 32) {
        int f = lane & 15, n2 = lane >> 4;
        float s = bias[q * 16 + f];
#pragma unroll
        for (int gg = 0; gg < 16; ++gg) s += part[w][n2][gg][f];
        __builtin_nontemporal_store(
            s, dstp + (size_t)(c * 16 + w * 2 + n2) * 64 + q * 16 + f);
    }
    (void)ADD_BIAS_ONLY;
}

// R18: t2 = tanh(aggf) @ W2^T as bf16 (bias b1 already folded into aggf by
// agg_q). Same proven structure as bin_and_gemm1's GEMM path. Also writes
// T2's dummy zero pad row (node == N_NODES). NT stores go through uint2
// reinterpretation (__builtin_nontemporal_store rejects HIP_vector_type).
__global__ __launch_bounds__(256) void tanh_gemm2(const float* __restrict__ aggf,
                                                  const float* __restrict__ W2,
                                                  unsigned short* __restrict__ T2) {
    __shared__ float Ws[64 * 64];
    int tid = threadIdx.x;
#pragma unroll
    for (int j = 0; j < 16; ++j) Ws[j * 256 + tid] = W2[j * 256 + tid];
    __syncthreads();

    int n = blockIdx.x * 256 + tid;
    if (n > N_NODES) return;
    uint2* tp = (uint2*)(T2 + (size_t)n * 64);
    if (n == N_NODES) {   // dummy zero row (pad target for agg_out)
        uint2 z = {0, 0};
#pragma unroll
        for (int k = 0; k < 16; ++k) tp[k] = z;
        return;
    }

    float4 h[16];
    const float4* xp = (const float4*)(aggf + (size_t)n * 64);
#pragma unroll
    for (int k = 0; k < 16; ++k) {
        float4 v = xp[k];
        float4 t;
        float e;
        e = __expf(2.f * v.x); t.x = 1.f - 2.f / (e + 1.f);
        e = __expf(2.f * v.y); t.y = 1.f - 2.f / (e + 1.f);
        e = __expf(2.f * v.z); t.z = 1.f - 2.f / (e + 1.f);
        e = __expf(2.f * v.w); t.w = 1.f - 2.f / (e + 1.f);
        h[k] = t;
    }

    for (int fg = 0; fg < 16; ++fg) {
        float r[4];
#pragma unroll
        for (int fi = 0; fi < 4; ++fi) {
            int f = fg * 4 + fi;
            float acc = 0.f;
#pragma unroll
            for (int k4 = 0; k4 < 16; ++k4) {
                float4 wv = *(const float4*)&Ws[f * 64 + k4 * 4];
                float4 hv = h[k4];
                acc += hv.x * wv.x + hv.y * wv.y + hv.z * wv.z + hv.w * wv.w;
            }
            r[fi] = acc;
        }
        unsigned lo = ((unsigned)f2bf(r[1]) << 16) | (unsigned)f2bf(r[0]);
        unsigned hi = ((unsigned)f2bf(r[3]) << 16) | (unsigned)f2bf(r[2]);
        uint2 o; o.x = lo; o.y = hi;
        *(tp + fg) = o;
    }
}

extern "C" void kernel_launch(void* const* d_in, const int* in_sizes, int n_in,
                              void* d_out, int out_size, void* d_ws, size_t ws_size,
                              hipStream_t stream) {
    const float* feat = (const float*)d_in[0];
    const int*   src  = (const int*)d_in[1];
    const int*   dst  = (const int*)d_in[2];
    const float* W1   = (const float*)d_in[3];
    const float* b1   = (const float*)d_in[4];
    const float* W2   = (const float*)d_in[5];
    const float* b2   = (const float*)d_in[6];
    float* out = (float*)d_out;

    // ws layout (~40.7 MB; harness poisons 256 MB of ws -> plenty)
    int*            binned   = (int*)d_ws;                                // 196*12288 ints
    unsigned short* csr16    = (unsigned short*)(binned + NBK * CSR_CAP); // 784*3072 ushort
    unsigned*       nodeinfo = (unsigned*)(csr16 + NBK * 4 * QCAP);       // 50000
    int*            bcur     = (int*)(nodeinfo + N_NODES);                // 196*16
    unsigned short* t        = (unsigned short*)(bcur + NBK * 16 + 8);    // 50001*64 bf16
    unsigned short* t2       = t + (size_t)(N_NODES + 1) * 64;            // 50001*64 bf16
    float*          aggf     = (float*)(t2 + (size_t)(N_NODES + 1) * 64); // 50000*64 f32

    // ---- CSR build + layer-1 transform (overlapped) ----
    (void)hipMemsetAsync(bcur, 0, NBK * 16 * sizeof(int), stream);
    bin_and_gemm1<<<BIN_BLOCKS + GEMM_BLOCKS, 256, 0, stream>>>(
        src, dst, bcur, binned, feat, W1, t);
    build_csr<<<NBK * 4, 256, 0, stream>>>(binned, bcur, nodeinfo, csr16);

    // ---- Layer 1 aggregate, quarter-sliced: aggf = b1 + gather-sum(T) ----
    agg_q<false><<<NB_AGGQ, 512, 0, stream>>>(t, csr16, nodeinfo, b1, aggf);

    // ---- tanh + layer-2 transform: t2 = tanh(aggf) @ W2^T (bf16) ----
    tanh_gemm2<<<TG_BLOCKS, 256, 0, stream>>>(aggf, W2, t2);

    // ---- Layer 2 aggregate, quarter-sliced: out = b2 + gather-sum(t2) ----
    agg_q<true><<<NB_AGGQ, 512, 0, stream>>>(t2, csr16, nodeinfo, b2, out);
}

// Round 5
// 280.174 us; speedup vs baseline: 1.0979x; 1.0979x over previous
//
#include <hip/hip_runtime.h>

#define N_NODES 50000
#define N_EDGES 1600000
#define DIM 64
#define NBK 196          // buckets of 256 dst-nodes
#define BIN_BLOCKS 391   // ceil(1.6M / 4096)
#define CSR_CAP 12288    // per-bucket slots
#define QCAP 3072        // per-quarter slots (mult-16-padded mean ~2560, ~8-sigma margin)
#define GEMM_BLOCKS 197  // covers 50000 rows + dummy zero row
#define NB_AGGQ 12500    // sliced agg blocks: 4 quarters x 3125 chunks of 16 nodes
#define TG_BLOCKS 196    // tanh+W2 blocks: 196*256 = 50176 >= 50001
#define PLANE ((size_t)(N_NODES + 1) * 16)   // ushorts per feature-quarter plane

// f32 -> bf16 round-to-nearest-even
__device__ __forceinline__ unsigned short f2bf(float f) {
    union { float f; unsigned u; } v; v.f = f;
    unsigned r = v.u + 0x7FFF + ((v.u >> 16) & 1);
    return (unsigned short)(r >> 16);
}
__device__ __forceinline__ float bf2f(unsigned short h) {
    union { unsigned u; float f; } v; v.u = ((unsigned)h) << 16;  return v.f;
}
// packed-bf16 halves of a uint -> f32 (low ushort, high ushort)
__device__ __forceinline__ float blo(unsigned u) {
    union { unsigned u; float f; } v; v.u = u << 16; return v.f;
}
__device__ __forceinline__ float bhi(unsigned u) {
    union { unsigned u; float f; } v; v.u = u & 0xFFFF0000u; return v.f;
}

// R11-verbatim binning + GEMM1, except T is written QUARTER-MAJOR (R19):
// 4 planes of [50001][16] bf16, plane q = features q*16..q*16+15.
__global__ __launch_bounds__(256) void bin_and_gemm1(const int* __restrict__ src,
                                                     const int* __restrict__ dst,
                                                     int* __restrict__ bcur,
                                                     int* __restrict__ binned,
                                                     const float* __restrict__ X,
                                                     const float* __restrict__ W,
                                                     unsigned short* __restrict__ T) {
    __shared__ int cnt[NBK];
    __shared__ int lofs[NBK];
    __shared__ int shiftv[NBK];
    __shared__ int sb[256];
    __shared__ int stag[4096];
    __shared__ unsigned char stb[4096];
    __shared__ float Ws[64 * 64];
    int tid = threadIdx.x;

    if (blockIdx.x >= BIN_BLOCKS) {
        // ---------------- GEMM path (feat f32 -> T bf16 planes) ----------------
#pragma unroll
        for (int j = 0; j < 16; ++j) Ws[j * 256 + tid] = W[j * 256 + tid];
        __syncthreads();

        int n = (blockIdx.x - BIN_BLOCKS) * 256 + tid;
        if (n > N_NODES) return;
        if (n == N_NODES) {  // dummy zero row in all 4 planes (pad target for agg)
            uint2 z = {0, 0};
#pragma unroll
            for (int q = 0; q < 4; ++q) {
                uint2* zp = (uint2*)(T + q * PLANE + (size_t)n * 16);
                zp[0] = z; zp[1] = z; zp[2] = z; zp[3] = z;
            }
            return;
        }

        float4 x[16];
        const float4* xp = (const float4*)(X + (size_t)n * 64);
#pragma unroll
        for (int k = 0; k < 16; ++k) x[k] = xp[k];

        for (int fg = 0; fg < 16; ++fg) {
            float r[4];
#pragma unroll
            for (int fi = 0; fi < 4; ++fi) {
                int f = fg * 4 + fi;
                float acc = 0.f;
#pragma unroll
                for (int k4 = 0; k4 < 16; ++k4) {
                    float4 w = *(const float4*)&Ws[f * 64 + k4 * 4];
                    float4 xv = x[k4];
                    acc += xv.x * w.x + xv.y * w.y + xv.z * w.z + xv.w * w.w;
                }
                r[fi] = acc;
            }
            unsigned lo = ((unsigned)f2bf(r[1]) << 16) | (unsigned)f2bf(r[0]);
            unsigned hi = ((unsigned)f2bf(r[3]) << 16) | (unsigned)f2bf(r[2]);
            uint2 o; o.x = lo; o.y = hi;
            *((uint2*)(T + (fg >> 2) * PLANE + (size_t)n * 16) + (fg & 3)) = o;
        }
        return;
    }

    // ---------------- Binning path (R6-proven) ----------------
    if (tid < NBK) cnt[tid] = 0;
    __syncthreads();

    int base = blockIdx.x * 4096;
    int nedge = N_EDGES - base;
    if (nedge > 4096) nedge = 4096;

    int myb[16], myr[16], myp[16];
#pragma unroll
    for (int i = 0; i < 16; ++i) {
        int e = base + i * 256 + tid;
        myb[i] = -1;
        if (e < N_EDGES) {
            int s = src[e], d = dst[e];
            int b = d >> 8;
            myb[i] = b;
            myp[i] = ((d & 255) << 16) | s;
            myr[i] = atomicAdd(&cnt[b], 1);
        }
    }
    __syncthreads();

    int c = (tid < NBK) ? cnt[tid] : 0;
    sb[tid] = c;
    __syncthreads();
    for (int off = 1; off < 256; off <<= 1) {
        int u = (tid >= off) ? sb[tid - off] : 0;
        __syncthreads();
        sb[tid] += u;
        __syncthreads();
    }
    if (tid < NBK) {
        lofs[tid] = sb[tid] - c;
        if (c) shiftv[tid] = tid * CSR_CAP + atomicAdd(&bcur[tid * 16], c) - lofs[tid];
    }
    __syncthreads();

#pragma unroll
    for (int i = 0; i < 16; ++i) {
        if (myb[i] >= 0) {
            int idx = lofs[myb[i]] + myr[i];
            stag[idx] = myp[i];
            stb[idx] = (unsigned char)myb[i];
        }
    }
    __syncthreads();

    for (int i = tid; i < nedge; i += 256)
        binned[i + shiftv[stb[i]]] = stag[i];
}

// R11-verbatim: one workgroup per (bucket, dst-quarter). Counts padded to
// mult-16 with dummy src = N_NODES (zero row). nodeinfo=(pcnt<<23)|pos, pos%16==0.
__global__ __launch_bounds__(256) void build_csr(const int* __restrict__ binned,
                                                 const int* __restrict__ bcur,
                                                 unsigned* __restrict__ nodeinfo,
                                                 unsigned short* __restrict__ csr16) {
    __shared__ int cnt[64], cnt2[64], ofs[64], sb[64];
    __shared__ int qtot;
    int tid = threadIdx.x;
    int b = blockIdx.x >> 2;
    int q = blockIdx.x & 3;
    int ibase = b * CSR_CAP;
    int qbase = (b * 4 + q) * QCAP;
    int m = bcur[b * 16];          // zero-based bucket edge count
    if (m > CSR_CAP) m = CSR_CAP;
    if (tid < 64) { cnt[tid] = 0; cnt2[tid] = 0; }
    __syncthreads();

    for (int i = tid; i < m; i += 256) {
        int dl = (binned[ibase + i] >> 16) & 255;
        if ((dl >> 6) == q) atomicAdd(&cnt[dl & 63], 1);
    }
    __syncthreads();

    int v = 0;
    if (tid < 64) { v = (cnt[tid] + 15) & ~15; sb[tid] = v; }  // mult-16 pad
    __syncthreads();
    for (int off = 1; off < 64; off <<= 1) {
        int u = (tid >= off && tid < 64) ? sb[tid - off] : 0;
        __syncthreads();
        if (tid < 64) sb[tid] += u;
        __syncthreads();
    }
    if (tid < 64) {
        ofs[tid] = sb[tid] - v;
        int node = (b << 8) + (q << 6) + tid;
        if (node < N_NODES)
            nodeinfo[node] = ((unsigned)v << 23) | (unsigned)(qbase + ofs[tid]);
    }
    if (tid == 63) qtot = sb[63];
    __syncthreads();

    int qt = qtot;
    for (int i = tid; i < qt; i += 256) csr16[qbase + i] = (unsigned short)N_NODES;
    __syncthreads();

    for (int i = tid; i < m; i += 256) {
        int p = binned[ibase + i];
        int dl = (p >> 16) & 255;
        if ((dl >> 6) == q) {
            int r = atomicAdd(&cnt2[dl & 63], 1);
            csr16[qbase + ofs[dl & 63] + r] = (unsigned short)(p & 0xFFFF);
        }
    }
}

// Accumulate one uint4 (8 bf16 feature values) into 8 f32 accumulators.
#define ACC8(d)                                                     \
    a0 += blo(d.x); a1 += bhi(d.x); a2 += blo(d.y); a3 += bhi(d.y); \
    a4 += blo(d.z); a5 += bhi(d.z); a6 += blo(d.w); a7 += bhi(d.w);

// R19: quarter-sliced gather over CONTIGUOUS per-quarter planes (R18 fix:
// column-slicing a row-major T left the L2 footprint at 6.4MB since lines
// are 128B; planes make quarter q's working set a contiguous 1.6MB ->
// L2-resident on its XCD pair, 100% line utilization, FETCH should collapse).
// q = blockIdx&3 rides the round-robin block->XCD dispatch (XCD = blk%8, so
// quarter q -> XCDs {q, q+4}). 256 thr / 16 nodes per block; 4 nodes/wave;
// lane = ns(2b)<<4 | g(3b)<<1 | fs(1b): group g reads edge chunk slot, fs
// picks 8-feature half (uint4 = 16B). Reduce over g = 3 __shfl_xor rounds
// (masks 2/4/8 touch only g bits) -> ZERO LDS, 8 blocks/CU thread-cap.
// nt8 = pcnt>>3 is even (pcnt mult-16) -> exact unroll-2, no tail.
// dstp[node*64 + q*16 + f] (f32), bias folded in at write.
template <int PASS>   // 0: aggf = b1 + agg(T);  1: out = b2 + agg(T2)
__global__ __launch_bounds__(256) void agg_q(const unsigned short* __restrict__ T,
                                             const unsigned short* __restrict__ csr,
                                             const unsigned* __restrict__ nodeinfo,
                                             const float* __restrict__ bias,
                                             float* __restrict__ dstp) {
    int tid = threadIdx.x;
    int w = tid >> 6, lane = tid & 63;
    int ns = lane >> 4;           // node within wave (0..3)
    int g  = (lane >> 1) & 7;     // edge-group slot (8-edge chunks)
    int fs = lane & 1;            // feature half (8 features = 16B)
    int q  = blockIdx.x & 3;
    int c  = blockIdx.x >> 2;     // 0..3124
    int node = c * 16 + w * 4 + ns;

    unsigned info = __builtin_nontemporal_load(nodeinfo + node);
    int pos = (int)(info & 0x7FFFFFu);
    int nt8 = (int)(info >> 23) >> 3;    // 8-edge chunks, even
    const unsigned short* ip = csr + pos + g;
    const uint4* Tq = (const uint4*)(T + q * PLANE);
    float a0 = 0.f, a1 = 0.f, a2 = 0.f, a3 = 0.f, a4 = 0.f, a5 = 0.f, a6 = 0.f, a7 = 0.f;
    for (int k = 0; k < nt8; k += 2) {
        int j0 = __builtin_nontemporal_load(ip + k * 8);
        int j1 = __builtin_nontemporal_load(ip + k * 8 + 8);
        uint4 d0 = Tq[(size_t)j0 * 2 + fs];
        uint4 d1 = Tq[(size_t)j1 * 2 + fs];
        ACC8(d0) ACC8(d1)
    }

    // reduce across the 8 edge-groups: 3 butterfly rounds over g bits
#pragma unroll
    for (int m = 2; m <= 8; m <<= 1) {
        a0 += __shfl_xor(a0, m); a1 += __shfl_xor(a1, m);
        a2 += __shfl_xor(a2, m); a3 += __shfl_xor(a3, m);
        a4 += __shfl_xor(a4, m); a5 += __shfl_xor(a5, m);
        a6 += __shfl_xor(a6, m); a7 += __shfl_xor(a7, m);
    }

    if (g == 0) {
        const float4* bp = (const float4*)(bias + q * 16 + fs * 8);
        float4 b01 = bp[0], b23 = bp[1];
        float* op = dstp + (size_t)node * 64 + q * 16 + fs * 8;
        float4 o0 = {a0 + b01.x, a1 + b01.y, a2 + b01.z, a3 + b01.w};
        float4 o1 = {a4 + b23.x, a5 + b23.y, a6 + b23.z, a7 + b23.w};
        *(float4*)op = o0;
        *(float4*)(op + 4) = o1;
    }
}

// R18: t2 = tanh(aggf) @ W2^T as bf16 planes (b1 already folded into aggf).
// Writes T2 quarter-major (R19) incl. the dummy zero pad row (node==N_NODES).
__global__ __launch_bounds__(256) void tanh_gemm2(const float* __restrict__ aggf,
                                                  const float* __restrict__ W2,
                                                  unsigned short* __restrict__ T2) {
    __shared__ float Ws[64 * 64];
    int tid = threadIdx.x;
#pragma unroll
    for (int j = 0; j < 16; ++j) Ws[j * 256 + tid] = W2[j * 256 + tid];
    __syncthreads();

    int n = blockIdx.x * 256 + tid;
    if (n > N_NODES) return;
    if (n == N_NODES) {   // dummy zero row in all 4 planes
        uint2 z = {0, 0};
#pragma unroll
        for (int q = 0; q < 4; ++q) {
            uint2* zp = (uint2*)(T2 + q * PLANE + (size_t)n * 16);
            zp[0] = z; zp[1] = z; zp[2] = z; zp[3] = z;
        }
        return;
    }

    float4 h[16];
    const float4* xp = (const float4*)(aggf + (size_t)n * 64);
#pragma unroll
    for (int k = 0; k < 16; ++k) {
        float4 v = xp[k];
        float4 t;
        float e;
        e = __expf(2.f * v.x); t.x = 1.f - 2.f / (e + 1.f);
        e = __expf(2.f * v.y); t.y = 1.f - 2.f / (e + 1.f);
        e = __expf(2.f * v.z); t.z = 1.f - 2.f / (e + 1.f);
        e = __expf(2.f * v.w); t.w = 1.f - 2.f / (e + 1.f);
        h[k] = t;
    }

    for (int fg = 0; fg < 16; ++fg) {
        float r[4];
#pragma unroll
        for (int fi = 0; fi < 4; ++fi) {
            int f = fg * 4 + fi;
            float acc = 0.f;
#pragma unroll
            for (int k4 = 0; k4 < 16; ++k4) {
                float4 wv = *(const float4*)&Ws[f * 64 + k4 * 4];
                float4 hv = h[k4];
                acc += hv.x * wv.x + hv.y * wv.y + hv.z * wv.z + hv.w * wv.w;
            }
            r[fi] = acc;
        }
        unsigned lo = ((unsigned)f2bf(r[1]) << 16) | (unsigned)f2bf(r[0]);
        unsigned hi = ((unsigned)f2bf(r[3]) << 16) | (unsigned)f2bf(r[2]);
        uint2 o; o.x = lo; o.y = hi;
        *((uint2*)(T2 + (fg >> 2) * PLANE + (size_t)n * 16) + (fg & 3)) = o;
    }
}

extern "C" void kernel_launch(void* const* d_in, const int* in_sizes, int n_in,
                              void* d_out, int out_size, void* d_ws, size_t ws_size,
                              hipStream_t stream) {
    const float* feat = (const float*)d_in[0];
    const int*   src  = (const int*)d_in[1];
    const int*   dst  = (const int*)d_in[2];
    const float* W1   = (const float*)d_in[3];
    const float* b1   = (const float*)d_in[4];
    const float* W2   = (const float*)d_in[5];
    const float* b2   = (const float*)d_in[6];
    float* out = (float*)d_out;

    // ws layout (~40.7 MB; harness poisons 256 MB of ws -> plenty)
    int*            binned   = (int*)d_ws;                                // 196*12288 ints
    unsigned short* csr16    = (unsigned short*)(binned + NBK * CSR_CAP); // 784*3072 ushort
    unsigned*       nodeinfo = (unsigned*)(csr16 + NBK * 4 * QCAP);       // 50000
    int*            bcur     = (int*)(nodeinfo + N_NODES);                // 196*16
    unsigned short* t        = (unsigned short*)(bcur + NBK * 16 + 8);    // 4 planes bf16
    unsigned short* t2       = t + 4 * PLANE;                             // 4 planes bf16
    float*          aggf     = (float*)(t2 + 4 * PLANE);                  // 50000*64 f32

    // ---- CSR build + layer-1 transform (overlapped) ----
    (void)hipMemsetAsync(bcur, 0, NBK * 16 * sizeof(int), stream);
    bin_and_gemm1<<<BIN_BLOCKS + GEMM_BLOCKS, 256, 0, stream>>>(
        src, dst, bcur, binned, feat, W1, t);
    build_csr<<<NBK * 4, 256, 0, stream>>>(binned, bcur, nodeinfo, csr16);

    // ---- Layer 1 aggregate, quarter-plane-sliced: aggf = b1 + gather-sum(T) ----
    agg_q<0><<<NB_AGGQ, 256, 0, stream>>>(t, csr16, nodeinfo, b1, aggf);

    // ---- tanh + layer-2 transform: t2 = tanh(aggf) @ W2^T (bf16 planes) ----
    tanh_gemm2<<<TG_BLOCKS, 256, 0, stream>>>(aggf, W2, t2);

    // ---- Layer 2 aggregate, quarter-plane-sliced: out = b2 + gather-sum(t2) ----
    agg_q<1><<<NB_AGGQ, 256, 0, stream>>>(t2, csr16, nodeinfo, b2, out);
}

// Round 7
// 226.854 us; speedup vs baseline: 1.3559x; 1.2350x over previous
//
#include <hip/hip_runtime.h>

#define N_NODES 50000
#define N_EDGES 1600000
#define DIM 64
#define NBK 196          // buckets of 256 dst-nodes
#define BIN_BLOCKS 391   // ceil(1.6M / 4096)
#define CSR_CAP 12288    // per-bucket slots = 8 octants x OCT_CAP
#define OCT_CAP 1536     // per-(bucket,octant) slots (mean 1024, +16 sigma)
#define QCAP 3072        // per-quarter slots (mult-16-padded mean ~2560, ~8-sigma margin)
#define GEMM_BLOCKS 197  // covers 50000 rows + dummy zero row
#define NB_AGG8 6250     // aggregate blocks (8 nodes/block; 6250*8 == 50000 exactly)

// f32 -> bf16 round-to-nearest-even
__device__ __forceinline__ unsigned short f2bf(float f) {
    union { float f; unsigned u; } v; v.f = f;
    unsigned r = v.u + 0x7FFF + ((v.u >> 16) & 1);
    return (unsigned short)(r >> 16);
}
__device__ __forceinline__ float bf2f(unsigned short h) {
    union { unsigned u; float f; } v; v.u = ((unsigned)h) << 16;  return v.f;
}
// packed-bf16 halves of a uint -> f32 (low ushort, high ushort)
__device__ __forceinline__ float blo(unsigned u) {
    union { unsigned u; float f; } v; v.u = u << 16; return v.f;
}
__device__ __forceinline__ float bhi(unsigned u) {
    union { unsigned u; float f; } v; v.u = u & 0xFFFF0000u; return v.f;
}

// R20: binning + GEMM1. Binning now assigns slots within per-(bucket,octant)
// regions (oct = blockIdx&7): global atomic contention per counter drops
// 391 -> ~49 concurrent RMWs (R19 post-mortem: the 49us was per-address
// atomic serialization, occupancy 7.9% / VALUBusy 15% rule out BW/VALU).
__global__ __launch_bounds__(256) void bin_and_gemm1(const int* __restrict__ src,
                                                     const int* __restrict__ dst,
                                                     int* __restrict__ bcur,
                                                     int* __restrict__ binned,
                                                     const float* __restrict__ X,
                                                     const float* __restrict__ W,
                                                     unsigned short* __restrict__ T) {
    __shared__ int cnt[NBK];
    __shared__ int lofs[NBK];
    __shared__ int shiftv[NBK];
    __shared__ int sb[256];
    __shared__ int stag[4096];
    __shared__ unsigned char stb[4096];
    __shared__ float Ws[64 * 64];
    int tid = threadIdx.x;

    if (blockIdx.x >= BIN_BLOCKS) {
        // ---------------- GEMM path (feat f32 -> T bf16) ----------------
#pragma unroll
        for (int j = 0; j < 16; ++j) Ws[j * 256 + tid] = W[j * 256 + tid];
        __syncthreads();

        int n = (blockIdx.x - BIN_BLOCKS) * 256 + tid;
        if (n > N_NODES) return;
        ushort4* tp = (ushort4*)(T + (size_t)n * 64);
        if (n == N_NODES) {  // dummy zero row (pad target for agg1)
            ushort4 z = {0, 0, 0, 0};
#pragma unroll
            for (int k = 0; k < 16; ++k) tp[k] = z;
            return;
        }

        float4 x[16];
        const float4* xp = (const float4*)(X + (size_t)n * 64);
#pragma unroll
        for (int k = 0; k < 16; ++k) x[k] = xp[k];

        for (int fg = 0; fg < 16; ++fg) {
            float r[4];
#pragma unroll
            for (int fi = 0; fi < 4; ++fi) {
                int f = fg * 4 + fi;
                float acc = 0.f;
#pragma unroll
                for (int k4 = 0; k4 < 16; ++k4) {
                    float4 w = *(const float4*)&Ws[f * 64 + k4 * 4];
                    float4 xv = x[k4];
                    acc += xv.x * w.x + xv.y * w.y + xv.z * w.z + xv.w * w.w;
                }
                r[fi] = acc;
            }
            ushort4 o;
            o.x = f2bf(r[0]); o.y = f2bf(r[1]); o.z = f2bf(r[2]); o.w = f2bf(r[3]);
            tp[fg] = o;
        }
        return;
    }

    // ---------------- Binning path (R6-proven core, R20 oct-split) ----------------
    if (tid < NBK) cnt[tid] = 0;
    __syncthreads();

    int base = blockIdx.x * 4096;
    int oct = blockIdx.x & 7;
    int nedge = N_EDGES - base;
    if (nedge > 4096) nedge = 4096;

    int myb[16], myr[16], myp[16];
#pragma unroll
    for (int i = 0; i < 16; ++i) {
        int e = base + i * 256 + tid;
        myb[i] = -1;
        if (e < N_EDGES) {
            int s = src[e], d = dst[e];
            int b = d >> 8;
            myb[i] = b;
            myp[i] = ((d & 255) << 16) | s;
            myr[i] = atomicAdd(&cnt[b], 1);
        }
    }
    __syncthreads();

    int c = (tid < NBK) ? cnt[tid] : 0;
    sb[tid] = c;
    __syncthreads();
    for (int off = 1; off < 256; off <<= 1) {
        int u = (tid >= off) ? sb[tid - off] : 0;
        __syncthreads();
        sb[tid] += u;
        __syncthreads();
    }
    if (tid < NBK) {
        lofs[tid] = sb[tid] - c;
        if (c) shiftv[tid] = tid * CSR_CAP + oct * OCT_CAP
                           + atomicAdd(&bcur[(tid * 8 + oct) * 16], c) - lofs[tid];
    }
    __syncthreads();

#pragma unroll
    for (int i = 0; i < 16; ++i) {
        if (myb[i] >= 0) {
            int idx = lofs[myb[i]] + myr[i];
            stag[idx] = myp[i];
            stb[idx] = (unsigned char)myb[i];
        }
    }
    __syncthreads();

    for (int i = tid; i < nedge; i += 256)
        binned[i + shiftv[stb[i]]] = stag[i];
}

// R20: one workgroup per (bucket, dst-quarter); scans the bucket's 8 octant
// regions. Pad-fill is now per-node tail writes (<=15 each) instead of a
// qtot-wide dummy fill. nodeinfo=(pcnt<<23)|pos, pos%16==0, pcnt mult-16.
__global__ __launch_bounds__(256) void build_csr(const int* __restrict__ binned,
                                                 const int* __restrict__ bcur,
                                                 unsigned* __restrict__ nodeinfo,
                                                 unsigned short* __restrict__ csr16) {
    __shared__ int cnt[64], cnt2[64], ofs[64], sb[64];
    __shared__ int mo[8];
    int tid = threadIdx.x;
    int b = blockIdx.x >> 2;
    int q = blockIdx.x & 3;
    int qbase = (b * 4 + q) * QCAP;
    if (tid < 64) { cnt[tid] = 0; cnt2[tid] = 0; }
    if (tid < 8) {
        int m = bcur[(b * 8 + tid) * 16];
        mo[tid] = m > OCT_CAP ? OCT_CAP : m;
    }
    __syncthreads();

    for (int oct = 0; oct < 8; ++oct) {
        int ibase = b * CSR_CAP + oct * OCT_CAP;
        int m = mo[oct];
        for (int i = tid; i < m; i += 256) {
            int dl = (binned[ibase + i] >> 16) & 255;
            if ((dl >> 6) == q) atomicAdd(&cnt[dl & 63], 1);
        }
    }
    __syncthreads();

    int v = 0, myc = 0;
    if (tid < 64) { myc = cnt[tid]; v = (myc + 15) & ~15; sb[tid] = v; }  // mult-16 pad
    __syncthreads();
    for (int off = 1; off < 64; off <<= 1) {
        int u = (tid >= off && tid < 64) ? sb[tid - off] : 0;
        __syncthreads();
        if (tid < 64) sb[tid] += u;
        __syncthreads();
    }
    if (tid < 64) {
        int o = sb[tid] - v;
        ofs[tid] = o;
        int node = (b << 8) + (q << 6) + tid;
        if (node < N_NODES)
            nodeinfo[node] = ((unsigned)v << 23) | (unsigned)(qbase + o);
        for (int i = myc; i < v; ++i)          // pad tail with dummy src
            csr16[qbase + o + i] = (unsigned short)N_NODES;
    }
    __syncthreads();

    for (int oct = 0; oct < 8; ++oct) {
        int ibase = b * CSR_CAP + oct * OCT_CAP;
        int m = mo[oct];
        for (int i = tid; i < m; i += 256) {
            int p = binned[ibase + i];
            int dl = (p >> 16) & 255;
            if ((dl >> 6) == q) {
                int r = atomicAdd(&cnt2[dl & 63], 1);
                csr16[qbase + ofs[dl & 63] + r] = (unsigned short)(p & 0xFFFF);
            }
        }
    }
}

// Accumulate one uint4 (8 bf16 feature values) into 8 f32 accumulators.
#define ACC8(d)                                                     \
    a0 += blo(d.x); a1 += bhi(d.x); a2 += blo(d.y); a3 += bhi(d.y); \
    a4 += blo(d.z); a5 += bhi(d.z); a6 += blo(d.w); a7 += bhi(d.w);

// R17-verbatim agg_fuse1 (proven ~46us; R19's quarter-plane slicing made the
// gather L2-resident but NOT faster -> per-request-bound, full-row gather with
// 100% line utilization is the right shape). 512 thr / 8 nodes; 4-deep unroll;
// single barrier; W2 epilogue fused (no tanh_gemm2 kernel).
__global__ __launch_bounds__(512) void agg_fuse1(const unsigned short* __restrict__ T,
                                                 const unsigned short* __restrict__ csr,
                                                 const unsigned* __restrict__ nodeinfo,
                                                 const float* __restrict__ b1,
                                                 const float* __restrict__ W2,
                                                 unsigned short* __restrict__ T2) {
    __shared__ __align__(16) float4 W2t4[1024];     // 16 KB (W2 transposed, lane-striped)
    __shared__ __align__(16) float part[8][8][72];  // 18 KB (per-wave partials; row0 doubles as h)
    int tid = threadIdx.x;
    int w = tid >> 6;
    int lane = tid & 63;
    int g8 = lane >> 3;
    int fs = lane & 7;
    int node = blockIdx.x * 8 + w;

    // stage W2 transposed (read after the single barrier below)
    for (int L4 = tid; L4 < 1024; L4 += 512) {
        int k4 = L4 >> 6, f = L4 & 63;
        W2t4[L4] = *(const float4*)(W2 + f * 64 + k4 * 4);
    }

    // ---- gather-accumulate: 8 rows/load, 4 loads in flight ----
    unsigned info = __builtin_nontemporal_load(nodeinfo + node);
    float bias = b1[lane];
    int pos = (int)(info & 0x7FFFFFu);
    int nch = (int)(info >> 23) >> 3;   // 8-edge chunks, even (pcnt mult 16)
    const unsigned short* ip = csr + pos + g8;
    const uint4* Tp = (const uint4*)T;
    float a0 = 0.f, a1 = 0.f, a2 = 0.f, a3 = 0.f, a4 = 0.f, a5 = 0.f, a6 = 0.f, a7 = 0.f;
    int c = 0;
    for (; c + 4 <= nch; c += 4) {
        int j0 = __builtin_nontemporal_load(ip + c * 8);
        int j1 = __builtin_nontemporal_load(ip + c * 8 + 8);
        int j2 = __builtin_nontemporal_load(ip + c * 8 + 16);
        int j3 = __builtin_nontemporal_load(ip + c * 8 + 24);
        uint4 d0 = Tp[j0 * 8 + fs];
        uint4 d1 = Tp[j1 * 8 + fs];
        uint4 d2 = Tp[j2 * 8 + fs];
        uint4 d3 = Tp[j3 * 8 + fs];
        ACC8(d0) ACC8(d1) ACC8(d2) ACC8(d3)
    }
    if (c < nch) {   // remaining 2 chunks (nch even)
        int j0 = __builtin_nontemporal_load(ip + c * 8);
        int j1 = __builtin_nontemporal_load(ip + c * 8 + 8);
        uint4 d0 = Tp[j0 * 8 + fs];
        uint4 d1 = Tp[j1 * 8 + fs];
        ACC8(d0) ACC8(d1)
    }
    float4 pa = {a0, a1, a2, a3};
    float4 pb = {a4, a5, a6, a7};
    *(float4*)&part[w][g8][fs * 8] = pa;
    *(float4*)&part[w][g8][fs * 8 + 4] = pb;
    __syncthreads();   // covers W2t4 staging (part is wave-private)

    // reduce 8 groups: lane = feature
    float acc = bias;
#pragma unroll
    for (int g = 0; g < 8; ++g) acc += part[w][g][lane];

    // ---- tanh + in-block 64x64 GEMM epilogue (h overlaid in part row 0) ----
    float e = __expf(2.f * acc);
    part[w][0][lane] = 1.f - 2.f / (e + 1.f);   // after all part reads (lockstep wave)

    const float* hrow = &part[w][0][0];
    float tf = 0.f;
#pragma unroll
    for (int k4 = 0; k4 < 16; ++k4) {
        float4 hv = *(const float4*)(hrow + k4 * 4);   // broadcast
        float4 wv = W2t4[k4 * 64 + lane];
        tf += hv.x * wv.x + hv.y * wv.y + hv.z * wv.z + hv.w * wv.w;
    }
    T2[(size_t)node * DIM + lane] = f2bf(tf);

    // zero T2's dummy pad row (block 0 only; agg2 gathers it for padding)
    if (blockIdx.x == 0 && tid < 64)
        T2[(size_t)N_NODES * DIM + tid] = 0;
}

// R17-verbatim agg_out: out = gather-sum(T2) + b2, f32. No barrier.
__global__ __launch_bounds__(512) void agg_out(const unsigned short* __restrict__ T,
                                               const unsigned short* __restrict__ csr,
                                               const unsigned* __restrict__ nodeinfo,
                                               const float* __restrict__ bias,
                                               float* __restrict__ outp) {
    __shared__ __align__(16) float part[8][8][72];  // 18 KB, wave-private
    int tid = threadIdx.x;
    int w = tid >> 6;
    int lane = tid & 63;
    int g8 = lane >> 3;
    int fs = lane & 7;
    int node = blockIdx.x * 8 + w;   // grid*8 == 50000 exactly

    unsigned info = __builtin_nontemporal_load(nodeinfo + node);
    float bv = bias[lane];
    int pos = (int)(info & 0x7FFFFFu);
    int nch = (int)(info >> 23) >> 3;
    const unsigned short* ip = csr + pos + g8;
    const uint4* Tp = (const uint4*)T;
    float a0 = 0.f, a1 = 0.f, a2 = 0.f, a3 = 0.f, a4 = 0.f, a5 = 0.f, a6 = 0.f, a7 = 0.f;
    int c = 0;
    for (; c + 4 <= nch; c += 4) {
        int j0 = __builtin_nontemporal_load(ip + c * 8);
        int j1 = __builtin_nontemporal_load(ip + c * 8 + 8);
        int j2 = __builtin_nontemporal_load(ip + c * 8 + 16);
        int j3 = __builtin_nontemporal_load(ip + c * 8 + 24);
        uint4 d0 = Tp[j0 * 8 + fs];
        uint4 d1 = Tp[j1 * 8 + fs];
        uint4 d2 = Tp[j2 * 8 + fs];
        uint4 d3 = Tp[j3 * 8 + fs];
        ACC8(d0) ACC8(d1) ACC8(d2) ACC8(d3)
    }
    if (c < nch) {
        int j0 = __builtin_nontemporal_load(ip + c * 8);
        int j1 = __builtin_nontemporal_load(ip + c * 8 + 8);
        uint4 d0 = Tp[j0 * 8 + fs];
        uint4 d1 = Tp[j1 * 8 + fs];
        ACC8(d0) ACC8(d1)
    }
    float4 pa = {a0, a1, a2, a3};
    float4 pb = {a4, a5, a6, a7};
    *(float4*)&part[w][g8][fs * 8] = pa;
    *(float4*)&part[w][g8][fs * 8 + 4] = pb;
    // part is wave-private: wave-internal DS ordering suffices, no barrier

    float acc = bv;
#pragma unroll
    for (int g = 0; g < 8; ++g) acc += part[w][g][lane];
    __builtin_nontemporal_store(acc, outp + (size_t)node * DIM + lane);
}

extern "C" void kernel_launch(void* const* d_in, const int* in_sizes, int n_in,
                              void* d_out, int out_size, void* d_ws, size_t ws_size,
                              hipStream_t stream) {
    const float* feat = (const float*)d_in[0];
    const int*   src  = (const int*)d_in[1];
    const int*   dst  = (const int*)d_in[2];
    const float* W1   = (const float*)d_in[3];
    const float* b1   = (const float*)d_in[4];
    const float* W2   = (const float*)d_in[5];
    const float* b2   = (const float*)d_in[6];
    float* out = (float*)d_out;

    // ws layout (~28 MB; harness poisons 256 MB of ws -> plenty)
    int*            binned   = (int*)d_ws;                                // 196*12288 ints
    unsigned short* csr16    = (unsigned short*)(binned + NBK * CSR_CAP); // 784*3072 ushort
    unsigned*       nodeinfo = (unsigned*)(csr16 + NBK * 4 * QCAP);       // 50000
    int*            bcur     = (int*)(nodeinfo + N_NODES);                // 196*8*16 ints
    unsigned short* t        = (unsigned short*)(bcur + NBK * 8 * 16 + 8); // 50001*64 bf16
    unsigned short* t2       = t + (size_t)(N_NODES + 1) * 64;            // 50001*64 bf16

    // ---- CSR build + layer-1 transform (overlapped) ----
    (void)hipMemsetAsync(bcur, 0, NBK * 8 * 16 * sizeof(int), stream);
    bin_and_gemm1<<<BIN_BLOCKS + GEMM_BLOCKS, 256, 0, stream>>>(
        src, dst, bcur, binned, feat, W1, t);
    build_csr<<<NBK * 4, 256, 0, stream>>>(binned, bcur, nodeinfo, csr16);

    // ---- Layer 1 aggregate + fused layer-2 transform: t2 = tanh(agg+b1)@W2^T ----
    agg_fuse1<<<NB_AGG8, 512, 0, stream>>>(t, csr16, nodeinfo, b1, W2, t2);

    // ---- Layer 2 aggregate: out = agg(t2) + b2, f32 ----
    agg_out<<<NB_AGG8, 512, 0, stream>>>(t2, csr16, nodeinfo, b2, out);
}